// Round 10
// baseline (377.885 us; speedup 1.0000x reference)
//
#include <hip/hip_runtime.h>
#include <math.h>

#define SEQLEN 2048
#define DIN 2048
#define NH 32
#define NKV 8
#define HD 64
#define DQ (NH*HD)    // 2048
#define DKV (NKV*HD)  // 512

using u16 = unsigned short;
using u32 = unsigned int;
using bf16x8 = __attribute__((ext_vector_type(8))) __bf16;
using f32x4  = __attribute__((ext_vector_type(4))) float;

__device__ __forceinline__ u16 f2b(float f) {
    union { float f; u32 u; } x; x.f = f;
    u32 u = x.u;
    u32 r = (u + 0x7fffu + ((u >> 16) & 1u)) >> 16;   // RNE
    return (u16)r;
}
__device__ __forceinline__ u32 fbits(float f) {
    union { float f; u32 u; } x; x.f = f; return x.u;
}

// async global->LDS, 16B/lane; lds base wave-uniform, lane i writes i*16B.
__device__ __forceinline__ void gl2lds16(const u16* g, u16* l) {
    __builtin_amdgcn_global_load_lds(
        (const __attribute__((address_space(1))) void*)g,
        (__attribute__((address_space(3))) void*)l,
        16, 0, 0);
}

// --- 16-row x 32-k chunks (512 u16) for GEMM tiles --------------------------
// loading lane -> (row = lane&15, koct = lane>>4); elem (row,kk) at
// chunk*512 + (kk>>3)*128 + (row&15)*8 + (kk&7).
__device__ __forceinline__ int lds_off32(int row, int kk0) {
    return (row >> 4) * 512 + (kk0 >> 3) * 128 + (row & 15) * 8;
}

// ---------------------------------------------------------------------------
// Fused prep: cast x -> bf16; transpose-cast wq/wk/wv (contiguous [3072][2048])
// and wo.
// ---------------------------------------------------------------------------
__global__ __launch_bounds__(256) void prep(const float* __restrict__ x,
                                            const float* __restrict__ wq,
                                            const float* __restrict__ wk,
                                            const float* __restrict__ wv,
                                            const float* __restrict__ wo,
                                            u16* __restrict__ xb,
                                            u16* __restrict__ wqkvT,
                                            u16* __restrict__ woT) {
    const int b = blockIdx.x;
    const int t = threadIdx.x;
    if (b < 4096) {
        int i = b * 1024 + t * 4;
        float4 v = *reinterpret_cast<const float4*>(&x[i]);
        ushort4 o;
        o.x = f2b(v.x); o.y = f2b(v.y); o.z = f2b(v.z); o.w = f2b(v.w);
        *reinterpret_cast<ushort4*>(&xb[i]) = o;
        return;
    }
    __shared__ float tile[32][33];
    int b2 = b - 4096;
    const float* src; u16* dst; int C, bx, by;
    if (b2 < 4096)      { src = wq; dst = wqkvT;                           C = 2048; bx = b2 & 63; by = b2 >> 6; }
    else if (b2 < 5120) { b2 -= 4096; src = wk; dst = wqkvT + (size_t)2048 * 2048; C = 512; bx = b2 & 15; by = b2 >> 4; }
    else if (b2 < 6144) { b2 -= 5120; src = wv; dst = wqkvT + (size_t)2560 * 2048; C = 512; bx = b2 & 15; by = b2 >> 4; }
    else                { b2 -= 6144; src = wo; dst = woT;                 C = 2048; bx = b2 & 63; by = b2 >> 6; }
    const int c0 = bx * 32, r0 = by * 32;
    const int tr = t >> 5, tc = t & 31;
    #pragma unroll
    for (int i = 0; i < 4; ++i)
        tile[tr + i * 8][tc] = src[(size_t)(r0 + tr + i * 8) * C + c0 + tc];
    __syncthreads();
    #pragma unroll
    for (int i = 0; i < 4; ++i)
        dst[(size_t)(c0 + tr + i * 8) * 2048 + r0 + tc] = f2b(tile[tc][tr + i * 8]);
}

// ---------------------------------------------------------------------------
// bf16 MFMA GEMM v4: BM=64, BN=128, BK=32, 128 threads (2 waves), double-
// buffered glds prefetch (one barrier/step). Wave w computes all 64 rows x
// its 64-col strip (4x4 16-tiles = 16 MFMAs per step, 8 b128 LDS reads).
// Grids: QKV 768 blocks (3/CU), wo 512 (2/CU) -- co-resident blocks hide
// the barrier's vmcnt(0) drain (r9: 1-1.5 blocks/CU exposed it fully).
// MODE 0: fp32 C. MODE 1: QKV epilogue -- wave strip = one head: fused
// RMSNorm+RoPE for Q/K; V transposed + column-interleaved within each
// 64-seq block: pos(kv) = (b4*2+(kv>>5))*8 + ((kv>>4)&1)*4 + (kv&3),
// b4=(kv>>2)&3, enabling full-K=32 PV MFMAs in attention.
// ---------------------------------------------------------------------------
template<int MODE>
__global__ __launch_bounds__(128) void gemm_glds(const u16* __restrict__ A,
                                                 const u16* __restrict__ Bt,
                                                 float* __restrict__ Cf,
                                                 u16* __restrict__ Qb,
                                                 u16* __restrict__ Kb,
                                                 u16* __restrict__ VtG,
                                                 const float* __restrict__ cosb,
                                                 const float* __restrict__ sinb,
                                                 const float* __restrict__ qnw,
                                                 const float* __restrict__ knw,
                                                 int M, int N, int K) {
    __shared__ u16 As[2][64 * 32];    // 4 chunks (16r x 32k) per buf
    __shared__ u16 Bs[2][128 * 32];   // 8 chunks per buf
    const int t = threadIdx.x;
    const int w = t >> 6, lane = t & 63, quad = lane >> 4, l15 = lane & 15;
    const int m0 = blockIdx.y * 64, n0 = blockIdx.x * 128;
    const int wc = w * 64;
    const int srow = lane & 15, skoct = (lane >> 4) * 8;

    f32x4 acc[4][4];
    #pragma unroll
    for (int mt = 0; mt < 4; ++mt)
        #pragma unroll
        for (int nt = 0; nt < 4; ++nt)
            #pragma unroll
            for (int r = 0; r < 4; ++r) acc[mt][nt][r] = 0.0f;

    auto stage = [&](int buf, int k0) {
        #pragma unroll
        for (int i = 0; i < 2; ++i) {
            int c = w * 2 + i;   // A chunks 0..3
            gl2lds16(A + (size_t)(m0 + c * 16 + srow) * K + k0 + skoct, &As[buf][c * 512]);
        }
        #pragma unroll
        for (int i = 0; i < 4; ++i) {
            int c = w * 4 + i;   // B chunks 0..7
            gl2lds16(Bt + (size_t)(n0 + c * 16 + srow) * K + k0 + skoct, &Bs[buf][c * 512]);
        }
    };

    stage(0, 0);
    const int nsteps = K >> 5;
    for (int st = 0; st < nsteps; ++st) {
        const int buf = st & 1;
        __syncthreads();                          // prefetched buf ready
        if (st + 1 < nsteps) stage(buf ^ 1, (st + 1) << 5);
        const int kk0 = quad * 8;
        bf16x8 a[4], b[4];
        #pragma unroll
        for (int mt = 0; mt < 4; ++mt)
            a[mt] = *reinterpret_cast<const bf16x8*>(&As[buf][lds_off32(mt * 16 + l15, kk0)]);
        #pragma unroll
        for (int nt = 0; nt < 4; ++nt)
            b[nt] = *reinterpret_cast<const bf16x8*>(&Bs[buf][lds_off32(wc + nt * 16 + l15, kk0)]);
        #pragma unroll
        for (int mt = 0; mt < 4; ++mt)
            #pragma unroll
            for (int nt = 0; nt < 4; ++nt)
                acc[mt][nt] = __builtin_amdgcn_mfma_f32_16x16x32_bf16(a[mt], b[nt], acc[mt][nt], 0, 0, 0);
    }

    if (MODE == 0) {
        #pragma unroll
        for (int mt = 0; mt < 4; ++mt)
            #pragma unroll
            for (int nt = 0; nt < 4; ++nt) {
                const int rb  = m0 + mt * 16 + quad * 4;
                const int col = n0 + wc + nt * 16 + l15;
                #pragma unroll
                for (int r = 0; r < 4; ++r)
                    Cf[(size_t)(rb + r) * N + col] = acc[mt][nt][r];
            }
        return;
    }

    // ---- MODE 1 epilogue: wave strip = one head ----
    const int hb = n0 + wc;
    if (hb >= 2560) {                      // V: transposed, interleaved columns
        #pragma unroll
        for (int mt = 0; mt < 4; ++mt) {
            const int rb  = m0 + mt * 16 + quad * 4;        // seq base (4-aligned)
            const int s64 = rb & 63;
            const int a4  = (s64 >> 4) & 3, b4 = (s64 >> 2) & 3;
            const int colp = (rb & ~63) + (b4 * 2 + (a4 >> 1)) * 8 + (a4 & 1) * 4;
            #pragma unroll
            for (int nt = 0; nt < 4; ++nt) {
                const int d = hb - 2560 + nt * 16 + l15;
                ushort4 o;
                o.x = f2b(acc[mt][nt][0]); o.y = f2b(acc[mt][nt][1]);
                o.z = f2b(acc[mt][nt][2]); o.w = f2b(acc[mt][nt][3]);
                *reinterpret_cast<ushort4*>(&VtG[(size_t)d * 2048 + colp]) = o;
            }
        }
        return;
    }

    const bool isQ = hb < 2048;
    const float* nw = isQ ? qnw : knw;
    float wv_[4];
    #pragma unroll
    for (int nt = 0; nt < 4; ++nt) wv_[nt] = nw[nt * 16 + l15];

    #pragma unroll
    for (int mt = 0; mt < 4; ++mt) {
        float s2[4] = {0.f, 0.f, 0.f, 0.f};
        #pragma unroll
        for (int nt = 0; nt < 4; ++nt)
            #pragma unroll
            for (int r = 0; r < 4; ++r) s2[r] += acc[mt][nt][r] * acc[mt][nt][r];
        #pragma unroll
        for (int off = 1; off < 16; off <<= 1)
            #pragma unroll
            for (int r = 0; r < 4; ++r) s2[r] += __shfl_xor(s2[r], off);

        float vn[4][4];
        #pragma unroll
        for (int r = 0; r < 4; ++r) {
            float rin = rsqrtf(s2[r] * (1.0f / 64.0f) + 1e-6f);
            #pragma unroll
            for (int nt = 0; nt < 4; ++nt) vn[nt][r] = acc[mt][nt][r] * rin * wv_[nt];
        }

        #pragma unroll
        for (int r = 0; r < 4; ++r) {
            const int s = m0 + mt * 16 + quad * 4 + r;
            #pragma unroll
            for (int nt = 0; nt < 4; ++nt) {
                const int d = nt * 16 + l15;
                float c  = cosb[s * 64 + d];
                float sn = sinb[s * 64 + d];
                float sgn = (nt < 2) ? -1.0f : 1.0f;     // rotate_half
                float res = vn[nt][r] * c + sgn * vn[nt ^ 2][r] * sn;
                if (isQ) {
                    res *= 0.18033688f;                   // 0.125 * log2(e)
                    Qb[(size_t)s * 2048 + hb + d] = f2b(res);
                } else {
                    Kb[(size_t)s * 512 + hb - 2048 + d] = f2b(res);
                }
            }
        }
    }
}

// ---------------------------------------------------------------------------
// MFMA flash attention v5: ZERO LDS, ZERO BARRIERS. K and V A-frags are read
// directly from global (per-kvh K+V working set = 512 KB; whole KV = 4 MB ->
// L2-resident; each b128's 4-lane group reads 64B contiguous). Every wave is
// fully independent -- latency hidden by occupancy, not lockstep barriers.
// Grid 1024: qt = 31-(b>>5) (heavy first), kvh=(b&31)>>2, h=kvh*4+(b&3).
// Wave w owns q-rows q0+w*16..+15. Fixed-shift softmax p=exp2(s-24).
// PV uses full-K=32 MFMAs via the column-interleaved V layout.
// ---------------------------------------------------------------------------
__global__ __launch_bounds__(256) void attn_fused(const u16* __restrict__ Qb,
                                                  const u16* __restrict__ Kb,
                                                  const u16* __restrict__ VtG,
                                                  u16* __restrict__ attnb) {
    const int b    = blockIdx.x;
    const int qt   = 31 - (b >> 5);
    const int q0   = qt * 64;
    const int kvh  = (b & 31) >> 2;
    const int h    = kvh * 4 + (b & 3);
    const int t    = threadIdx.x;
    const int w    = t >> 6, lane = t & 63, quad = lane >> 4, l15 = lane & 15;
    const int qrow = q0 + w * 16 + l15;

    // Q B-frags (exp2-scaled)
    const u16* qr = Qb + (size_t)qrow * DQ + h * HD;
    bf16x8 qB[2];
    qB[0] = *reinterpret_cast<const bf16x8*>(qr + quad * 8);
    qB[1] = *reinterpret_cast<const bf16x8*>(qr + 32 + quad * 8);

    // per-lane base pointers for K / V frag loads
    const u16* kbase = Kb + (size_t)l15 * DKV + kvh * HD + quad * 8;   // + (k0+kt4*16)*DKV + ks*32
    const u16* vbase = VtG + (size_t)(kvh * HD + l15) * 2048 + quad * 16;  // rows dt*16, col k0+pair*8

    f32x4 o[4];
    #pragma unroll
    for (int dt = 0; dt < 4; ++dt)
        #pragma unroll
        for (int r = 0; r < 4; ++r) o[dt][r] = 0.0f;
    float lpart = 0.0f;

    for (int kt = 0; kt <= qt; ++kt) {
        const int k0 = kt * 64;

        // S^T = K . Q^T : A-frags straight from global
        f32x4 s[4];
        #pragma unroll
        for (int kt4 = 0; kt4 < 4; ++kt4)
            #pragma unroll
            for (int r = 0; r < 4; ++r) s[kt4][r] = 0.0f;
        #pragma unroll
        for (int ks = 0; ks < 2; ++ks)
            #pragma unroll
            for (int kt4 = 0; kt4 < 4; ++kt4) {
                bf16x8 ka = *reinterpret_cast<const bf16x8*>(
                    kbase + (size_t)(k0 + kt4 * 16) * DKV + ks * 32);
                s[kt4] = __builtin_amdgcn_mfma_f32_16x16x32_bf16(ka, qB[ks], s[kt4], 0, 0, 0);
            }

        if (kt == qt) {   // wave-uniform: only the diagonal tile masks
            const int qi = w * 16 + l15;
            #pragma unroll
            for (int kt4 = 0; kt4 < 4; ++kt4)
                #pragma unroll
                for (int r = 0; r < 4; ++r)
                    if ((kt4 * 16 + quad * 4 + r) > qi) s[kt4][r] = -1e30f;
        }

        // exp2 + pack P^T B-frags
        u32 pb[4][2];
        #pragma unroll
        for (int kt4 = 0; kt4 < 4; ++kt4) {
            float p[4];
            #pragma unroll
            for (int r = 0; r < 4; ++r) {
                p[r] = exp2f(s[kt4][r] - 24.0f);
                lpart += p[r];
            }
            pb[kt4][0] = __builtin_amdgcn_perm(fbits(p[1]), fbits(p[0]), 0x07060302u);
            pb[kt4][1] = __builtin_amdgcn_perm(fbits(p[3]), fbits(p[2]), 0x07060302u);
        }

        // O^T += V^T . P^T : full-K=32 MFMAs, V frags direct from global
        #pragma unroll
        for (int pair = 0; pair < 2; ++pair) {
            union { bf16x8 v; u32 u[4]; } pu;
            pu.u[0] = pb[pair * 2][0];     pu.u[1] = pb[pair * 2][1];
            pu.u[2] = pb[pair * 2 + 1][0]; pu.u[3] = pb[pair * 2 + 1][1];
            #pragma unroll
            for (int dt = 0; dt < 4; ++dt) {
                bf16x8 va = *reinterpret_cast<const bf16x8*>(
                    vbase + (size_t)(dt * 16) * 2048 + k0 + pair * 8);
                o[dt] = __builtin_amdgcn_mfma_f32_16x16x32_bf16(va, pu.v, o[dt], 0, 0, 0);
            }
        }
    }

    lpart += __shfl_xor(lpart, 16);
    lpart += __shfl_xor(lpart, 32);
    float inv = 1.0f / lpart;

    #pragma unroll
    for (int dt = 0; dt < 4; ++dt) {
        ushort4 ov;
        ov.x = f2b(o[dt][0] * inv);
        ov.y = f2b(o[dt][1] * inv);
        ov.z = f2b(o[dt][2] * inv);
        ov.w = f2b(o[dt][3] * inv);
        *reinterpret_cast<ushort4*>(attnb + (size_t)qrow * DQ + h * HD + dt * 16 + quad * 4) = ov;
    }
}

// ---------------------------------------------------------------------------
extern "C" void kernel_launch(void* const* d_in, const int* in_sizes, int n_in,
                              void* d_out, int out_size, void* d_ws, size_t ws_size,
                              hipStream_t stream) {
    const float* x    = (const float*)d_in[0];
    const float* cosb = (const float*)d_in[1];
    const float* sinb = (const float*)d_in[2];
    const float* wq   = (const float*)d_in[3];
    const float* wk   = (const float*)d_in[4];
    const float* wv   = (const float*)d_in[5];
    const float* wo   = (const float*)d_in[6];
    const float* qnw  = (const float*)d_in[7];
    const float* knw  = (const float*)d_in[8];
    float* out = (float*)d_out;

    char* ws = (char*)d_ws;
    const size_t MB = 1024 * 1024;
    u16* xb    = (u16*)(ws + 0);          // 8 MB
    u16* wqkvT = (u16*)(ws + 8  * MB);    // 12 MB: [wq^T; wk^T; wv^T] [3072][2048]
    u16* woT   = (u16*)(ws + 20 * MB);    // 8 MB
    u16* Qb    = (u16*)(ws + 28 * MB);    // 8 MB
    u16* Kb    = (u16*)(ws + 36 * MB);    // 2 MB
    u16* VtG   = (u16*)(ws + 38 * MB);    // 2 MB  [512][2048] col-interleaved
    u16* attnb = (u16*)(ws + 40 * MB);    // 8 MB

    // 1) prep: cast x + weight transposes
    prep<<<14336, 256, 0, stream>>>(x, wq, wk, wv, wo, xb, wqkvT, woT);

    // 2) fused QKV projection w/ RMSNorm+RoPE epilogue (V transposed+interleaved)
    gemm_glds<1><<<dim3(3072 / 128, SEQLEN / 64), 128, 0, stream>>>(
        xb, wqkvT, nullptr, Qb, Kb, VtG, cosb, sinb, qnw, knw, SEQLEN, 3072, DIN);

    // 3) GQA causal flash attention v5 (no LDS, no barriers)
    attn_fused<<<1024, 256, 0, stream>>>(Qb, Kb, VtG, attnb);

    // 4) output projection
    gemm_glds<0><<<dim3(DIN / 128, SEQLEN / 64), 128, 0, stream>>>(
        attnb, woT, out, nullptr, nullptr, nullptr, nullptr, nullptr, nullptr, nullptr,
        SEQLEN, DIN, DQ);
}